// Round 1
// baseline (299.829 us; speedup 1.0000x reference)
//
#include <hip/hip_runtime.h>

#define HW 3136
#define CH 256
#define NJT 49
#define NPIX 25088  // 8*3136

typedef __attribute__((ext_vector_type(8))) short bf16x8;
typedef __attribute__((ext_vector_type(4))) float f32x4;
typedef unsigned short u16;
typedef unsigned int u32;

static __device__ __forceinline__ u16 f2bf(float f){
  union { float f; u32 u; } v; v.f = f;
  u32 r = v.u + 0x7FFFu + ((v.u >> 16) & 1u);
  return (u16)(r >> 16);
}

// ---------- prep: per-pixel L2 norm (fp32, matches reference), emit bf16 x and xn ----------
__global__ __launch_bounds__(256) void prep_norm(const float* __restrict__ x,
                                                 u16* __restrict__ x_bf,
                                                 u16* __restrict__ xn_bf){
  const int row  = blockIdx.x * 4 + (threadIdx.x >> 6);
  const int lane = threadIdx.x & 63;
  const float4 v = *(const float4*)(x + (size_t)row * CH + lane * 4);
  float ss = v.x*v.x + v.y*v.y + v.z*v.z + v.w*v.w;
  #pragma unroll
  for (int off = 32; off; off >>= 1) ss += __shfl_xor(ss, off);
  const float inv = rsqrtf(fmaxf(ss, 1e-12f));
  ushort4 xb, nb;
  xb.x = f2bf(v.x);     xb.y = f2bf(v.y);     xb.z = f2bf(v.z);     xb.w = f2bf(v.w);
  nb.x = f2bf(v.x*inv); nb.y = f2bf(v.y*inv); nb.z = f2bf(v.z*inv); nb.w = f2bf(v.w*inv);
  *(ushort4*)(x_bf  + (size_t)row*CH + lane*4) = xb;
  *(ushort4*)(xn_bf + (size_t)row*CH + lane*4) = nb;
}

// ---------- prep: W (CxC fp32, [cin][cout]) -> Wt bf16 [cout][cin] ----------
__global__ __launch_bounds__(256) void prep_wt(const float* __restrict__ W,
                                               u16* __restrict__ Wt){
  const int o = blockIdx.x, i = threadIdx.x;
  Wt[o*CH + i] = f2bf(W[i*CH + o]);
}

// ---------- t = x @ W, stored transposed: tT[b][c][j] (bf16) ----------
__global__ __launch_bounds__(256) void gemm_t(const u16* __restrict__ x_bf,
                                              const u16* __restrict__ Wt,
                                              u16* __restrict__ tT){
  const int jt = blockIdx.x, b = blockIdx.y;
  const int tid = threadIdx.x, wid = tid >> 6, lane = tid & 63;
  const int l15 = lane & 15, l4 = lane >> 4;
  const int j0 = jt * 64;
  const int jrow = j0 + wid*16 + l15;
  const u16* ap = x_bf + ((size_t)b*HW + jrow)*CH + l4*8;

  f32x4 acc[16];
  #pragma unroll
  for (int n = 0; n < 16; ++n) acc[n] = f32x4{0.f,0.f,0.f,0.f};

  #pragma unroll
  for (int ks = 0; ks < 8; ++ks){
    const bf16x8 a = *(const bf16x8*)(ap + ks*32);
    #pragma unroll
    for (int n0 = 0; n0 < 16; ++n0){
      const bf16x8 bb = *(const bf16x8*)(Wt + (n0*16 + l15)*CH + ks*32 + l4*8);
      acc[n0] = __builtin_amdgcn_mfma_f32_16x16x32_bf16(a, bb, acc[n0], 0, 0, 0);
    }
  }
  #pragma unroll
  for (int n0 = 0; n0 < 16; ++n0){
    const int c = n0*16 + l15;
    #pragma unroll
    for (int r = 0; r < 4; ++r){
      const int j = j0 + wid*16 + l4*4 + r;
      tT[((size_t)b*CH + c)*HW + j] = f2bf(acc[n0][r]);
    }
  }
}

// ---------- main: y[i] = sum_j relu(xn_i . xn_j)^2 * t[j]  (per batch) ----------
// grid (49, 8); 4 waves; wave w owns output rows [i0+16w, i0+16w+16).
__global__ __launch_bounds__(256) void ppm_main(const u16* __restrict__ xn,
                                                const u16* __restrict__ tT,
                                                float* __restrict__ out){
  __shared__ u16 sXJ[64*256];    // xn_J tile, chunk-swizzled
  __shared__ u16 sTJ[256*64];    // tT_J tile (c-major), chunk-swizzled
  __shared__ u16 sS[4][16*64];   // per-wave S strip, chunk-swizzled

  const int it = blockIdx.x, b = blockIdx.y;
  const int tid = threadIdx.x, wid = tid >> 6, lane = tid & 63;
  const int l15 = lane & 15, l4 = lane >> 4;
  const int i0 = it * 64;

  // QK A-fragments: this wave's 16 xn_I rows, all K=256, held in registers across the J loop
  bf16x8 aq[8];
  {
    const u16* p = xn + ((size_t)b*HW + i0 + wid*16 + l15)*CH + l4*8;
    #pragma unroll
    for (int ks = 0; ks < 8; ++ks) aq[ks] = *(const bf16x8*)(p + ks*32);
  }

  f32x4 accY[16];
  #pragma unroll
  for (int n = 0; n < 16; ++n) accY[n] = f32x4{0.f,0.f,0.f,0.f};

  for (int jt = 0; jt < NJT; ++jt){
    const int j0 = jt * 64;
    __syncthreads();  // previous iteration's readers done
    // ---- stage xn_J [64][256] and tT_J [256][64] (16B chunks, XOR-swizzled) ----
    #pragma unroll
    for (int q = 0; q < 8; ++q){
      const int m = q*256 + tid;
      { const int row = m >> 5, g = m & 31;
        *(bf16x8*)&sXJ[row*256 + ((g ^ (row & 7)) * 8)] =
          *(const bf16x8*)(xn + ((size_t)b*HW + j0 + row)*CH + g*8); }
      { const int row = m >> 3, g = m & 7;
        *(bf16x8*)&sTJ[row*64 + ((g ^ (row & 7)) * 8)] =
          *(const bf16x8*)(tT + ((size_t)b*CH + row)*HW + j0 + g*8); }
    }
    __syncthreads();  // tiles visible

    // ---- QK^T: S[16 rows][64 cols] for this wave ----
    f32x4 accS[4];
    #pragma unroll
    for (int n = 0; n < 4; ++n) accS[n] = f32x4{0.f,0.f,0.f,0.f};
    #pragma unroll
    for (int ks = 0; ks < 8; ++ks){
      #pragma unroll
      for (int n0 = 0; n0 < 4; ++n0){
        const int row = n0*16 + l15;
        const int ch  = ks*4 + l4;
        const bf16x8 bb = *(const bf16x8*)&sXJ[row*256 + ((ch ^ (row & 7)) * 8)];
        accS[n0] = __builtin_amdgcn_mfma_f32_16x16x32_bf16(aq[ks], bb, accS[n0], 0, 0, 0);
      }
    }

    // ---- relu^2 -> bf16 -> private LDS strip (swizzled) ----
    #pragma unroll
    for (int n0 = 0; n0 < 4; ++n0){
      #pragma unroll
      for (int r = 0; r < 4; ++r){
        const int row = l4*4 + r;           // strip row
        const int col = n0*16 + l15;        // j within tile
        float v = accS[n0][r];
        v = fmaxf(v, 0.f);
        v *= v;
        sS[wid][row*64 + (((col >> 3) ^ (row & 7)) * 8) + (col & 7)] = f2bf(v);
      }
    }
    __syncthreads();  // (conservative) S strips visible

    // ---- PV: Y[16][256] += S[16][64] @ tT_J^T ----
    #pragma unroll
    for (int ks = 0; ks < 2; ++ks){
      const int rowA = l15, chA = ks*4 + l4;
      const bf16x8 aa = *(const bf16x8*)&sS[wid][rowA*64 + ((chA ^ (rowA & 7)) * 8)];
      #pragma unroll
      for (int n0 = 0; n0 < 16; ++n0){
        const int rowB = n0*16 + l15, chB = ks*4 + l4;
        const bf16x8 bb = *(const bf16x8*)&sTJ[rowB*64 + ((chB ^ (rowB & 7)) * 8)];
        accY[n0] = __builtin_amdgcn_mfma_f32_16x16x32_bf16(aa, bb, accY[n0], 0, 0, 0);
      }
    }
  }

  // ---- store Y (fp32) ----
  #pragma unroll
  for (int n0 = 0; n0 < 16; ++n0){
    const int c = n0*16 + l15;
    #pragma unroll
    for (int r = 0; r < 4; ++r){
      const int i = i0 + wid*16 + l4*4 + r;
      out[((size_t)b*HW + i)*CH + c] = accY[n0][r];
    }
  }
}

extern "C" void kernel_launch(void* const* d_in, const int* in_sizes, int n_in,
                              void* d_out, int out_size, void* d_ws, size_t ws_size,
                              hipStream_t stream){
  const float* x = (const float*)d_in[0];
  const float* W = (const float*)d_in[1];
  float* out = (float*)d_out;
  char* ws = (char*)d_ws;

  const size_t SZ = (size_t)NPIX * CH * sizeof(u16);   // 12,845,056 bytes
  u16* x_bf  = (u16*)(ws);
  u16* xn_bf = (u16*)(ws + SZ);
  u16* tT    = (u16*)(ws + 2*SZ);
  u16* Wt    = (u16*)(ws + 3*SZ);

  prep_norm<<<NPIX/4, 256, 0, stream>>>(x, x_bf, xn_bf);
  prep_wt<<<CH, CH, 0, stream>>>(W, Wt);
  gemm_t<<<dim3(NJT, 8), 256, 0, stream>>>(x_bf, Wt, tT);
  ppm_main<<<dim3(NJT, 8), 256, 0, stream>>>(xn_bf, tT, out);
}

// Round 2
// 162.615 us; speedup vs baseline: 1.8438x; 1.8438x over previous
//
#include <hip/hip_runtime.h>

#define HW 3136
#define CH 256
#define NJT 49
#define NPIX 25088  // 8*3136

typedef __attribute__((ext_vector_type(8))) short bf16x8;
typedef __attribute__((ext_vector_type(4))) float f32x4;
typedef unsigned short u16;
typedef unsigned int u32;

static __device__ __forceinline__ u16 f2bf(float f){
  union { float f; u32 u; } v; v.f = f;
  u32 r = v.u + 0x7FFFu + ((v.u >> 16) & 1u);
  return (u16)(r >> 16);
}

static __device__ __forceinline__ void gload16(const void* g, void* l){
  __builtin_amdgcn_global_load_lds(
      (const __attribute__((address_space(1))) unsigned int*)g,
      (__attribute__((address_space(3))) unsigned int*)l, 16, 0, 0);
}

// ---------- prep: per-pixel L2 norm (fp32, matches reference), emit bf16 x and xn ----------
__global__ __launch_bounds__(256) void prep_norm(const float* __restrict__ x,
                                                 u16* __restrict__ x_bf,
                                                 u16* __restrict__ xn_bf){
  const int row  = blockIdx.x * 4 + (threadIdx.x >> 6);
  const int lane = threadIdx.x & 63;
  const float4 v = *(const float4*)(x + (size_t)row * CH + lane * 4);
  float ss = v.x*v.x + v.y*v.y + v.z*v.z + v.w*v.w;
  #pragma unroll
  for (int off = 32; off; off >>= 1) ss += __shfl_xor(ss, off);
  const float inv = rsqrtf(fmaxf(ss, 1e-12f));
  ushort4 xb, nb;
  xb.x = f2bf(v.x);     xb.y = f2bf(v.y);     xb.z = f2bf(v.z);     xb.w = f2bf(v.w);
  nb.x = f2bf(v.x*inv); nb.y = f2bf(v.y*inv); nb.z = f2bf(v.z*inv); nb.w = f2bf(v.w*inv);
  *(ushort4*)(x_bf  + (size_t)row*CH + lane*4) = xb;
  *(ushort4*)(xn_bf + (size_t)row*CH + lane*4) = nb;
}

// ---------- prep: W (CxC fp32, [cin][cout]) -> Wt bf16 [cout][cin] ----------
__global__ __launch_bounds__(256) void prep_wt(const float* __restrict__ W,
                                               u16* __restrict__ Wt){
  const int o = blockIdx.x, i = threadIdx.x;
  Wt[o*CH + i] = f2bf(W[i*CH + o]);
}

// ---------- t = x @ W, stored transposed: tT[b][c][j] (bf16), coalesced via LDS ----------
__global__ __launch_bounds__(256) void gemm_t(const u16* __restrict__ x_bf,
                                              const u16* __restrict__ Wt,
                                              u16* __restrict__ tT){
  __shared__ u16 sT[256*64];  // [c][j-chunk swizzled]
  const int jt = blockIdx.x, b = blockIdx.y;
  const int tid = threadIdx.x, wid = tid >> 6, lane = tid & 63;
  const int l15 = lane & 15, l4 = lane >> 4;
  const int j0 = jt * 64;
  const int jrow = j0 + wid*16 + l15;
  const u16* ap = x_bf + ((size_t)b*HW + jrow)*CH + l4*8;

  f32x4 acc[16];
  #pragma unroll
  for (int n = 0; n < 16; ++n) acc[n] = f32x4{0.f,0.f,0.f,0.f};

  #pragma unroll
  for (int ks = 0; ks < 8; ++ks){
    const bf16x8 a = *(const bf16x8*)(ap + ks*32);
    #pragma unroll
    for (int n0 = 0; n0 < 16; ++n0){
      const bf16x8 bb = *(const bf16x8*)(Wt + (n0*16 + l15)*CH + ks*32 + l4*8);
      acc[n0] = __builtin_amdgcn_mfma_f32_16x16x32_bf16(a, bb, acc[n0], 0, 0, 0);
    }
  }
  // frag -> LDS (b64 writes along j), swizzled chunks
  #pragma unroll
  for (int n0 = 0; n0 < 16; ++n0){
    const int c = n0*16 + l15;
    const int jloc = wid*16 + l4*4;
    const int gj = jloc >> 3;
    ushort4 w4;
    w4.x = f2bf(acc[n0][0]); w4.y = f2bf(acc[n0][1]);
    w4.z = f2bf(acc[n0][2]); w4.w = f2bf(acc[n0][3]);
    *(ushort4*)&sT[c*64 + ((gj ^ (c & 7)) * 8) + (jloc & 7)] = w4;
  }
  __syncthreads();
  // coalesced write-out: 8 lanes per c-row, 128B contiguous per row
  #pragma unroll
  for (int p = 0; p < 8; ++p){
    const int c = p*32 + (tid >> 3);
    const int q = tid & 7;
    const bf16x8 v = *(const bf16x8*)&sT[c*64 + ((q ^ (c & 7)) * 8)];
    *(bf16x8*)(tT + ((size_t)b*CH + c)*HW + j0 + q*8) = v;
  }
}

// ---------- main: y[i] = sum_j relu(xn_i . xn_j)^2 * t[j]  (per batch) ----------
// grid (49, 8); 4 waves (256 thr); 2 blocks/CU (72 KB LDS).
// QK swapped: wave (wqj,wqi) computes S^T block [32 j][32 i]; xn_I held in regs as B.
// PV: wave wid owns Y[64 i][64 c] (c-offset wid*64), m4 x n4 register blocking.
__global__ __launch_bounds__(256, 2) void ppm_main(const u16* __restrict__ xn,
                                                   const u16* __restrict__ tT,
                                                   float* __restrict__ out){
  __shared__ u16 sXJ[64*256];   // xn_J  [row j][32 chunks], chunk-swizzled by row&7
  __shared__ u16 sTJ[256*64];   // tT_J  [c][8 chunks], chunk-swizzled by c&7
  __shared__ u16 sS [64*64];    // S     [i][8 chunks], chunk-swizzled by i&7

  const int it = blockIdx.x, b = blockIdx.y;
  const int tid = threadIdx.x, wid = tid >> 6, lane = tid & 63;
  const int l15 = lane & 15, l4 = lane >> 4;
  const int i0 = it * 64;
  const int wqj = wid >> 1, wqi = wid & 1;

  // B-regs for QK: xn_I rows (i0 + wqi*32 + nb*16 + l15), k-chunk (kb*4 + l4)
  bf16x8 aq[2][8];
  #pragma unroll
  for (int nb = 0; nb < 2; ++nb){
    const u16* p = xn + ((size_t)b*HW + i0 + wqi*32 + nb*16 + l15)*CH + l4*8;
    #pragma unroll
    for (int kb = 0; kb < 8; ++kb) aq[nb][kb] = *(const bf16x8*)(p + kb*32);
  }

  f32x4 accY[4][4];
  #pragma unroll
  for (int mb = 0; mb < 4; ++mb)
    #pragma unroll
    for (int nb = 0; nb < 4; ++nb) accY[mb][nb] = f32x4{0.f,0.f,0.f,0.f};

  const int sx_rl = lane >> 5, sx_sc = lane & 31;   // sXJ staging lane parts
  const int st_cl = lane >> 3, st_sc = lane & 7;    // sTJ staging lane parts

  for (int jt = 0; jt < NJT; ++jt){
    const int j0 = jt * 64;
    // ---- stage via global_load_lds (linear dest, inverse-swizzled source) ----
    #pragma unroll
    for (int q = 0; q < 8; ++q){
      const int m = wid*8 + q;
      { const int row = 2*m + sx_rl;
        const int g = sx_sc ^ (row & 7);
        gload16(xn + ((size_t)b*HW + j0 + row)*CH + g*8, &sXJ[m*512]); }
      { const int c = 8*m + st_cl;
        const int g = st_sc ^ (c & 7);
        gload16(tT + ((size_t)b*CH + c)*HW + j0 + g*8, &sTJ[m*512]); }
    }
    __syncthreads();

    // ---- QK (swapped): S^T[j][i], A = sXJ rows j, B = aq (xn_I) ----
    f32x4 accS[2][2];
    #pragma unroll
    for (int mb = 0; mb < 2; ++mb)
      #pragma unroll
      for (int nb = 0; nb < 2; ++nb) accS[mb][nb] = f32x4{0.f,0.f,0.f,0.f};
    #pragma unroll
    for (int kb = 0; kb < 8; ++kb){
      bf16x8 a[2];
      #pragma unroll
      for (int mb = 0; mb < 2; ++mb){
        const int rj = wqj*32 + mb*16 + l15;
        const int gk = kb*4 + l4;
        a[mb] = *(const bf16x8*)&sXJ[rj*256 + ((gk ^ (rj & 7)) * 8)];
      }
      #pragma unroll
      for (int mb = 0; mb < 2; ++mb)
        #pragma unroll
        for (int nb = 0; nb < 2; ++nb)
          accS[mb][nb] = __builtin_amdgcn_mfma_f32_16x16x32_bf16(a[mb], aq[nb][kb], accS[mb][nb], 0, 0, 0);
    }
    // relu^2 -> bf16 -> sS[i][j] (one b64 per frag: 4 consecutive j, fixed i)
    #pragma unroll
    for (int mb = 0; mb < 2; ++mb)
      #pragma unroll
      for (int nb = 0; nb < 2; ++nb){
        const int i_loc = wqi*32 + nb*16 + l15;
        const int jloc  = wqj*32 + mb*16 + l4*4;
        const int gj = jloc >> 3;
        float v0 = fmaxf(accS[mb][nb][0], 0.f); v0 *= v0;
        float v1 = fmaxf(accS[mb][nb][1], 0.f); v1 *= v1;
        float v2 = fmaxf(accS[mb][nb][2], 0.f); v2 *= v2;
        float v3 = fmaxf(accS[mb][nb][3], 0.f); v3 *= v3;
        ushort4 w4; w4.x = f2bf(v0); w4.y = f2bf(v1); w4.z = f2bf(v2); w4.w = f2bf(v3);
        *(ushort4*)&sS[i_loc*64 + ((gj ^ (i_loc & 7)) * 8) + (jloc & 7)] = w4;
      }
    __syncthreads();

    // ---- PV: Y[64 i][64 c] per wave, m4 x n4 x k2 ----
    #pragma unroll
    for (int kb = 0; kb < 2; ++kb){
      bf16x8 sA[4], sB[4];
      #pragma unroll
      for (int mb = 0; mb < 4; ++mb){
        const int i = mb*16 + l15;
        const int gj = kb*4 + l4;
        sA[mb] = *(const bf16x8*)&sS[i*64 + ((gj ^ (i & 7)) * 8)];
      }
      #pragma unroll
      for (int nb = 0; nb < 4; ++nb){
        const int c = wid*64 + nb*16 + l15;
        const int gj = kb*4 + l4;
        sB[nb] = *(const bf16x8*)&sTJ[c*64 + ((gj ^ (c & 7)) * 8)];
      }
      #pragma unroll
      for (int mb = 0; mb < 4; ++mb)
        #pragma unroll
        for (int nb = 0; nb < 4; ++nb)
          accY[mb][nb] = __builtin_amdgcn_mfma_f32_16x16x32_bf16(sA[mb], sB[nb], accY[mb][nb], 0, 0, 0);
    }
    __syncthreads();
  }

  // ---- store Y (fp32) ----
  #pragma unroll
  for (int mb = 0; mb < 4; ++mb)
    #pragma unroll
    for (int nb = 0; nb < 4; ++nb)
      #pragma unroll
      for (int r = 0; r < 4; ++r)
        out[((size_t)b*HW + i0 + mb*16 + l4*4 + r)*CH + wid*64 + nb*16 + l15] = accY[mb][nb][r];
}

extern "C" void kernel_launch(void* const* d_in, const int* in_sizes, int n_in,
                              void* d_out, int out_size, void* d_ws, size_t ws_size,
                              hipStream_t stream){
  const float* x = (const float*)d_in[0];
  const float* W = (const float*)d_in[1];
  float* out = (float*)d_out;
  char* ws = (char*)d_ws;

  const size_t SZ = (size_t)NPIX * CH * sizeof(u16);   // 12,845,056 bytes
  u16* x_bf  = (u16*)(ws);
  u16* xn_bf = (u16*)(ws + SZ);
  u16* tT    = (u16*)(ws + 2*SZ);
  u16* Wt    = (u16*)(ws + 3*SZ);

  prep_norm<<<NPIX/4, 256, 0, stream>>>(x, x_bf, xn_bf);
  prep_wt<<<CH, CH, 0, stream>>>(W, Wt);
  gemm_t<<<dim3(NJT, 8), 256, 0, stream>>>(x_bf, Wt, tT);
  ppm_main<<<dim3(NJT, 8), 256, 0, stream>>>(xn_bf, tT, out);
}

// Round 3
// 156.488 us; speedup vs baseline: 1.9160x; 1.0391x over previous
//
#include <hip/hip_runtime.h>

#define HW 3136
#define CH 256
#define NJT 49
#define NIT 25
#define NPIX 25088  // 8*3136

typedef __attribute__((ext_vector_type(8))) short bf16x8;
typedef __attribute__((ext_vector_type(4))) float f32x4;
typedef __attribute__((ext_vector_type(16))) float f32x16;
typedef unsigned short u16;
typedef unsigned int u32;

static __device__ __forceinline__ u16 f2bf(float f){
  union { float f; u32 u; } v; v.f = f;
  u32 r = v.u + 0x7FFFu + ((v.u >> 16) & 1u);
  return (u16)(r >> 16);
}

static __device__ __forceinline__ void gload16(const void* g, void* l){
  __builtin_amdgcn_global_load_lds(
      (const __attribute__((address_space(1))) unsigned int*)g,
      (__attribute__((address_space(3))) unsigned int*)l, 16, 0, 0);
}

static __device__ __forceinline__ f32x16 zero16(){
  f32x16 v;
  #pragma unroll
  for (int e = 0; e < 16; ++e) v[e] = 0.f;
  return v;
}

// sS swizzle: add-rotate + XOR, bijective per row i
static __device__ __forceinline__ int ssw(int i, int c){
  return (((c + (i >> 3)) & 7) ^ (i & 7));
}

// ---------- prep: W (CxC fp32, [cin][cout]) -> Wt bf16 [cout][cin] ----------
__global__ __launch_bounds__(256) void prep_wt(const float* __restrict__ W,
                                               u16* __restrict__ Wt){
  const int o = blockIdx.x, i = threadIdx.x;
  Wt[o*CH + i] = f2bf(W[i*CH + o]);
}

// ---------- fused: row-norm (fp32) + xn emit + t = x @ W stored transposed tT[b][c][j] ----------
__global__ __launch_bounds__(256) void gemm_t(const float* __restrict__ x,
                                              const u16* __restrict__ Wt,
                                              u16* __restrict__ xn_bf,
                                              u16* __restrict__ tT){
  __shared__ u16 sT[256*64];  // [c][j-chunk swizzled]
  const int jt = blockIdx.x, b = blockIdx.y;
  const int tid = threadIdx.x, wid = tid >> 6, lane = tid & 63;
  const int l15 = lane & 15, l4 = lane >> 4;
  const int j0 = jt * 64;
  const int row = j0 + wid*16 + l15;
  const float* xp = x + ((size_t)b*HW + row)*CH + l4*8;

  // load this lane's 64 channels (8 chunks of 8), accumulate sum of squares
  float xv[8][8];
  float ss = 0.f;
  #pragma unroll
  for (int kb = 0; kb < 8; ++kb){
    const float4 v0 = *(const float4*)(xp + kb*32);
    const float4 v1 = *(const float4*)(xp + kb*32 + 4);
    xv[kb][0]=v0.x; xv[kb][1]=v0.y; xv[kb][2]=v0.z; xv[kb][3]=v0.w;
    xv[kb][4]=v1.x; xv[kb][5]=v1.y; xv[kb][6]=v1.z; xv[kb][7]=v1.w;
    #pragma unroll
    for (int e = 0; e < 8; ++e) ss += xv[kb][e]*xv[kb][e];
  }
  // reduce across the 4 lanes sharing this row (lane ^ 16, lane ^ 32)
  ss += __shfl_xor(ss, 16);
  ss += __shfl_xor(ss, 32);
  const float inv = rsqrtf(fmaxf(ss, 1e-12f));

  // build bf16 A-frags (x) and write xn = x*inv
  bf16x8 ax[8];
  #pragma unroll
  for (int kb = 0; kb < 8; ++kb){
    bf16x8 a, n;
    #pragma unroll
    for (int e = 0; e < 8; ++e){
      a[e] = (short)f2bf(xv[kb][e]);
      n[e] = (short)f2bf(xv[kb][e]*inv);
    }
    ax[kb] = a;
    *(bf16x8*)(xn_bf + ((size_t)b*HW + row)*CH + kb*32 + l4*8) = n;
  }

  // GEMM: t[j][c] = x[j][:] @ W[:, c]
  f32x4 acc[16];
  #pragma unroll
  for (int n = 0; n < 16; ++n) acc[n] = f32x4{0.f,0.f,0.f,0.f};
  #pragma unroll
  for (int kb = 0; kb < 8; ++kb){
    #pragma unroll
    for (int n0 = 0; n0 < 16; ++n0){
      const bf16x8 bb = *(const bf16x8*)(Wt + (n0*16 + l15)*CH + kb*32 + l4*8);
      acc[n0] = __builtin_amdgcn_mfma_f32_16x16x32_bf16(ax[kb], bb, acc[n0], 0, 0, 0);
    }
  }
  // frag -> LDS (b64 writes along j), swizzled chunks
  #pragma unroll
  for (int n0 = 0; n0 < 16; ++n0){
    const int c = n0*16 + l15;
    const int jloc = wid*16 + l4*4;
    const int gj = jloc >> 3;
    ushort4 w4;
    w4.x = f2bf(acc[n0][0]); w4.y = f2bf(acc[n0][1]);
    w4.z = f2bf(acc[n0][2]); w4.w = f2bf(acc[n0][3]);
    *(ushort4*)&sT[c*64 + ((gj ^ (c & 7)) * 8) + (jloc & 7)] = w4;
  }
  __syncthreads();
  // coalesced write-out: 8 lanes per c-row, 128B contiguous per row
  #pragma unroll
  for (int p = 0; p < 8; ++p){
    const int c = p*32 + (tid >> 3);
    const int q = tid & 7;
    const bf16x8 v = *(const bf16x8*)&sT[c*64 + ((q ^ (c & 7)) * 8)];
    *(bf16x8*)(tT + ((size_t)b*CH + c)*HW + j0 + q*8) = v;
  }
}

// ---------- main: y[i] = sum_j relu(xn_i . xn_j)^2 * t[j]  (per batch) ----------
// grid (25, 8); 512 threads = 8 waves; 1 block/CU (144 KB LDS), i-tile 128.
// QK (32x32x16, swapped): wave (wqj=wid>>2, wqi=wid&3) computes S^T[32 j][32 i]; xn_I in regs.
// PV (32x32x16): wave (wpi=wid>>2, wpc=wid&3) owns Y[64 i][64 c], 2x2 frags, k=4.
__global__ __launch_bounds__(512) void ppm_main(const u16* __restrict__ xn,
                                                const u16* __restrict__ tT,
                                                float* __restrict__ out){
  __shared__ u16 sXJ[2][64*256];   // xn_J, chunk-swizzled by row&7 (dbuf)
  __shared__ u16 sTJ[2][256*64];   // tT_J, chunk-swizzled by c&7   (dbuf)
  __shared__ u16 sS [128*64];      // S[i][j], ssw-swizzled

  const int it = blockIdx.x, b = blockIdx.y;
  const int tid = threadIdx.x, wid = tid >> 6, lane = tid & 63;
  const int l31 = lane & 31, hi = lane >> 5;
  const int i0 = it * 128;
  const int wqj = wid >> 2, wqi = wid & 3;
  const int wpi = wid >> 2, wpc = wid & 3;

  // B-regs for QK: xn_I col block (32 i), all K=256: 16 frags
  bf16x8 aq[16];
  {
    int irow = i0 + wqi*32 + l31;
    if (irow >= HW) irow = HW - 1;   // pad tile (it=24): duplicate row, result unused
    const u16* p = xn + ((size_t)b*HW + irow)*CH + hi*8;
    #pragma unroll
    for (int kb = 0; kb < 16; ++kb) aq[kb] = *(const bf16x8*)(p + kb*16);
  }

  f32x16 accY[2][2];
  #pragma unroll
  for (int mi = 0; mi < 2; ++mi)
    #pragma unroll
    for (int ni = 0; ni < 2; ++ni) accY[mi][ni] = zero16();

  const size_t xbase = (size_t)b*HW;
  const size_t tbase = (size_t)b*CH;

  // stage one J-tile (64 KB) into buffer `buf`: linear LDS dest, inverse-swizzled source
  auto STAGE = [&](int buf, int jt){
    const int j0 = jt * 64;
    #pragma unroll
    for (int q = 0; q < 4; ++q){
      const int m = q*512 + tid;
      { const int row = m >> 5, g = m & 31;
        gload16(xn + (xbase + j0 + row)*CH + ((g ^ (row & 7)) * 8), &sXJ[buf][m*8]); }
      { const int c = m >> 3, g = m & 7;
        gload16(tT + (tbase + c)*HW + j0 + ((g ^ (c & 7)) * 8), &sTJ[buf][m*8]); }
    }
  };

  auto ITER = [&](int buf, int jt, bool stg){
    if (stg) STAGE(buf ^ 1, jt + 1);

    // ---- QK: S^T[32 j][32 i], dual accumulation chains for ILP ----
    f32x16 sa = zero16(), sb = zero16();
    const int rj = wqj*32 + l31;
    const int rsw = rj & 7;
    #pragma unroll
    for (int kb = 0; kb < 16; kb += 2){
      const bf16x8 a0 = *(const bf16x8*)&sXJ[buf][rj*256 + (((kb*2 + hi)     ^ rsw) * 8)];
      const bf16x8 a1 = *(const bf16x8*)&sXJ[buf][rj*256 + (((kb*2 + 2 + hi) ^ rsw) * 8)];
      sa = __builtin_amdgcn_mfma_f32_32x32x16_bf16(a0, aq[kb],   sa, 0, 0, 0);
      sb = __builtin_amdgcn_mfma_f32_32x32x16_bf16(a1, aq[kb+1], sb, 0, 0, 0);
    }
    // relu^2 -> bf16 -> sS[i][j]
    const int i_loc = wqi*32 + l31;
    #pragma unroll
    for (int q = 0; q < 4; ++q){
      ushort4 w4;
      #pragma unroll
      for (int r = 0; r < 4; ++r){
        float v = sa[q*4 + r] + sb[q*4 + r];
        v = fmaxf(v, 0.f);
        v *= v;
        ((u16*)&w4)[r] = f2bf(v);
      }
      const int jb = q*8 + hi*4;          // j within 32 (base of 4)
      const int jl = wqj*32 + jb;         // j within 64
      *(ushort4*)&sS[i_loc*64 + ssw(i_loc, jl >> 3)*8 + (jb & 7)] = w4;
    }
    __syncthreads();   // sS visible; drains staged loads (issued one phase ago)

    // ---- PV: Y[64 i][64 c] per wave, 2x2 frags, k=4 ----
    #pragma unroll
    for (int kb = 0; kb < 4; ++kb){
      bf16x8 pa[2], pb[2];
      #pragma unroll
      for (int mi = 0; mi < 2; ++mi){
        const int i = wpi*64 + mi*32 + l31;
        pa[mi] = *(const bf16x8*)&sS[i*64 + ssw(i, kb*2 + hi)*8];
      }
      #pragma unroll
      for (int ni = 0; ni < 2; ++ni){
        const int c = wpc*64 + ni*32 + l31;
        pb[ni] = *(const bf16x8*)&sTJ[buf][c*64 + (((kb*2 + hi) ^ (c & 7)) * 8)];
      }
      #pragma unroll
      for (int mi = 0; mi < 2; ++mi)
        #pragma unroll
        for (int ni = 0; ni < 2; ++ni)
          accY[mi][ni] = __builtin_amdgcn_mfma_f32_32x32x16_bf16(pa[mi], pb[ni], accY[mi][ni], 0, 0, 0);
    }
    __syncthreads();   // PV done before next QK overwrites sS
  };

  STAGE(0, 0);
  __syncthreads();

  #pragma unroll 1
  for (int jt = 0; jt < NJT - 1; jt += 2){
    ITER(0, jt,     true);
    ITER(1, jt + 1, jt + 2 < NJT);
  }
  ITER(0, NJT - 1, false);   // NJT-1 = 48 (even) -> buffer 0

  // ---- store Y (fp32): C layout col=lane&31, row=(r&3)+8*(r>>2)+4*hi ----
  #pragma unroll
  for (int mi = 0; mi < 2; ++mi)
    #pragma unroll
    for (int ni = 0; ni < 2; ++ni)
      #pragma unroll
      for (int r = 0; r < 16; ++r){
        const int row = i0 + wpi*64 + mi*32 + (r & 3) + 8*(r >> 2) + 4*hi;
        if (row < HW)
          out[((size_t)b*HW + row)*CH + wpc*64 + ni*32 + l31] = accY[mi][ni][r];
      }
}

extern "C" void kernel_launch(void* const* d_in, const int* in_sizes, int n_in,
                              void* d_out, int out_size, void* d_ws, size_t ws_size,
                              hipStream_t stream){
  const float* x = (const float*)d_in[0];
  const float* W = (const float*)d_in[1];
  float* out = (float*)d_out;
  char* ws = (char*)d_ws;

  const size_t SZ = (size_t)NPIX * CH * sizeof(u16);   // 12,845,056 bytes
  u16* xn_bf = (u16*)(ws);
  u16* tT    = (u16*)(ws + SZ);
  u16* Wt    = (u16*)(ws + 2*SZ);

  prep_wt<<<CH, CH, 0, stream>>>(W, Wt);
  gemm_t<<<dim3(NJT, 8), 256, 0, stream>>>(x, Wt, xn_bf, tT);
  ppm_main<<<dim3(NIT, 8), 512, 0, stream>>>(xn_bf, tT, out);
}